// Round 1
// baseline (499.449 us; speedup 1.0000x reference)
//
#include <hip/hip_runtime.h>
#include <hip/hip_bf16.h>
#include <stdint.h>

#define M_DIM 8192
#define N_DIM 4096
#define K_DIM 4096

typedef __attribute__((ext_vector_type(8))) __bf16 bf16x8;
typedef __attribute__((ext_vector_type(4))) float f32x4;

__device__ inline unsigned short f2bf(float f) {
  unsigned u = __builtin_bit_cast(unsigned, f);
  u += 0x7FFF + ((u >> 16) & 1);   // round-to-nearest-even
  return (unsigned short)(u >> 16);
}

__device__ inline void async_copy16(const void* g, void* l) {
  __builtin_amdgcn_global_load_lds(
      (const __attribute__((address_space(1))) unsigned int*)g,
      (__attribute__((address_space(3))) unsigned int*)l, 16, 0, 0);
}

// ---------- kernel 1: x fp32 -> bf16 ----------
__global__ __launch_bounds__(256) void cvt_x_kernel(const float* __restrict__ x,
                                                    unsigned short* __restrict__ xb,
                                                    int n4) {
  int i = blockIdx.x * 256 + threadIdx.x;
  int stride = gridDim.x * 256;
  for (; i < n4; i += stride) {
    float4 v = reinterpret_cast<const float4*>(x)[i];
    ushort4 o;
    o.x = f2bf(v.x); o.y = f2bf(v.y); o.z = f2bf(v.z); o.w = f2bf(v.w);
    reinterpret_cast<ushort4*>(xb)[i] = o;
  }
}

// ---------- kernel 2: W_eff = (W_q - zero)*scale + 2*(A@B)^T, bf16 ----------
// grid: (O/64)*(I/64) = 64*64 blocks; each block does a 64(o) x 64(i) patch.
__global__ __launch_bounds__(256) void build_weff_kernel(
    const int* __restrict__ Wq, const float* __restrict__ scale,
    const float* __restrict__ zero, const float* __restrict__ A,
    const float* __restrict__ Bm, unsigned short* __restrict__ Weff) {
  __shared__ float sA[64 * 17];  // A rows, padded to kill bank conflicts
  __shared__ float sB[16 * 64];  // B cols
  int bo = blockIdx.x >> 6;      // o-tile
  int bi = blockIdx.x & 63;      // i-tile (== group index g, since GROUP=64)
  int o0 = bo * 64, i0 = bi * 64;
  int t = threadIdx.x;
  for (int j = t; j < 1024; j += 256) sA[(j >> 4) * 17 + (j & 15)] = A[i0 * 16 + j];
  for (int j = t; j < 1024; j += 256) sB[j] = Bm[(j >> 6) * N_DIM + o0 + (j & 63)];
  __syncthreads();
  for (int e = 0; e < 16; ++e) {
    int idx = e * 256 + t;       // 0..4095
    int oo = idx >> 6, ii = idx & 63;
    int o = o0 + oo;
    float sc = scale[o * 64 + bi];
    float zp = zero[o * 64 + bi];
    float w = ((float)Wq[(size_t)o * K_DIM + i0 + ii] - zp) * sc;
    float acc = 0.f;
#pragma unroll
    for (int r = 0; r < 16; ++r) acc += sA[ii * 17 + r] * sB[r * 64 + oo];
    w += 2.0f * acc;             // SCALING = 32/16
    Weff[(size_t)o * K_DIM + i0 + ii] = f2bf(w);
  }
}

// ---------- kernel 3: out = x_bf16 @ W_eff^T + bias  (m97-structure) ----------
__global__ __launch_bounds__(256) void gemm_kernel(
    const unsigned short* __restrict__ xb, const unsigned short* __restrict__ wb,
    const float* __restrict__ bias, float* __restrict__ out) {
  __shared__ unsigned short Abuf[128 * 64];
  __shared__ unsigned short Bbuf[128 * 64];

  int bid = blockIdx.x;
  // bijective XCD swizzle: 2048 blocks % 8 XCDs == 0
  int swz = (bid & 7) * (2048 / 8) + (bid >> 3);
  int mt = swz / (N_DIM / 128);
  int nt = swz % (N_DIM / 128);
  int m0 = mt * 128, n0 = nt * 128;

  int t = threadIdx.x;
  int wave = t >> 6, lane = t & 63;
  int wr = wave >> 1, wc = wave & 1;
  int lr = lane >> 4, lc = lane & 15;

  f32x4 acc[4][4];
#pragma unroll
  for (int i = 0; i < 4; ++i)
#pragma unroll
    for (int j = 0; j < 4; ++j) acc[i][j] = f32x4{0.f, 0.f, 0.f, 0.f};

  for (int k0 = 0; k0 < K_DIM; k0 += 64) {
    // stage A,B tiles: each 128 rows x 64 cols bf16 = 16KB, 4x256x16B insts
#pragma unroll
    for (int j = 0; j < 4; ++j) {
      int flat = j * 256 + t;    // 16B chunk id, 0..1023
      int row = flat >> 3;
      int ck = flat & 7;
      async_copy16(xb + (size_t)(m0 + row) * K_DIM + k0 + ck * 8, &Abuf[flat * 8]);
      async_copy16(wb + (size_t)(n0 + row) * K_DIM + k0 + ck * 8, &Bbuf[flat * 8]);
    }
    __syncthreads();   // drains vmcnt before consume
#pragma unroll
    for (int kk = 0; kk < 2; ++kk) {
      bf16x8 af[4], bfr[4];
#pragma unroll
      for (int mi = 0; mi < 4; ++mi)
        af[mi] = *reinterpret_cast<const bf16x8*>(
            &Abuf[(wr * 64 + mi * 16 + lc) * 64 + kk * 32 + lr * 8]);
#pragma unroll
      for (int ni = 0; ni < 4; ++ni)
        bfr[ni] = *reinterpret_cast<const bf16x8*>(
            &Bbuf[(wc * 64 + ni * 16 + lc) * 64 + kk * 32 + lr * 8]);
#pragma unroll
      for (int mi = 0; mi < 4; ++mi)
#pragma unroll
        for (int ni = 0; ni < 4; ++ni)
          acc[mi][ni] = __builtin_amdgcn_mfma_f32_16x16x32_bf16(
              af[mi], bfr[ni], acc[mi][ni], 0, 0, 0);
    }
    __syncthreads();   // protect LDS from next iteration's staging
  }

  // epilogue: C/D layout col=lane&15, row=(lane>>4)*4+j  [m89/m91]
#pragma unroll
  for (int ni = 0; ni < 4; ++ni) {
    int n = n0 + wc * 64 + ni * 16 + lc;
    float bv = bias[n];
#pragma unroll
    for (int mi = 0; mi < 4; ++mi) {
      int mb = m0 + wr * 64 + mi * 16 + lr * 4;
#pragma unroll
      for (int j = 0; j < 4; ++j)
        out[(size_t)(mb + j) * N_DIM + n] = acc[mi][ni][j] + bv;
    }
  }
}

extern "C" void kernel_launch(void* const* d_in, const int* in_sizes, int n_in,
                              void* d_out, int out_size, void* d_ws, size_t ws_size,
                              hipStream_t stream) {
  const float* x     = (const float*)d_in[0];
  const int*   Wq    = (const int*)d_in[1];
  const float* scale = (const float*)d_in[2];
  const float* zero  = (const float*)d_in[3];
  const float* lA    = (const float*)d_in[4];
  const float* lB    = (const float*)d_in[5];
  const float* bias  = (const float*)d_in[6];
  float* out = (float*)d_out;

  unsigned short* xb = (unsigned short*)d_ws;                                   // 64 MB
  unsigned short* wb = (unsigned short*)((char*)d_ws + (size_t)M_DIM * K_DIM * 2); // +32 MB

  cvt_x_kernel<<<2048, 256, 0, stream>>>(x, xb, (M_DIM * K_DIM) / 4);
  build_weff_kernel<<<4096, 256, 0, stream>>>(Wq, scale, zero, lA, lB, wb);
  gemm_kernel<<<2048, 256, 0, stream>>>(xb, wb, bias, out);
}

// Round 2
// 334.861 us; speedup vs baseline: 1.4915x; 1.4915x over previous
//
#include <hip/hip_runtime.h>
#include <hip/hip_bf16.h>
#include <stdint.h>

#define M_DIM 8192
#define N_DIM 4096
#define K_DIM 4096

typedef __attribute__((ext_vector_type(8))) __bf16 bf16x8;
typedef __attribute__((ext_vector_type(4))) float f32x4;

__device__ inline unsigned short f2bf(float f) {
  unsigned u = __builtin_bit_cast(unsigned, f);
  u += 0x7FFF + ((u >> 16) & 1);   // round-to-nearest-even
  return (unsigned short)(u >> 16);
}

__device__ inline void async_copy16(const void* g, void* l) {
  __builtin_amdgcn_global_load_lds(
      (const __attribute__((address_space(1))) unsigned int*)g,
      (__attribute__((address_space(3))) unsigned int*)l, 16, 0, 0);
}

// ---------- kernel 1: x fp32 -> bf16 ----------
__global__ __launch_bounds__(256) void cvt_x_kernel(const float* __restrict__ x,
                                                    unsigned short* __restrict__ xb,
                                                    int n4) {
  int i = blockIdx.x * 256 + threadIdx.x;
  int stride = gridDim.x * 256;
  for (; i < n4; i += stride) {
    float4 v = reinterpret_cast<const float4*>(x)[i];
    ushort4 o;
    o.x = f2bf(v.x); o.y = f2bf(v.y); o.z = f2bf(v.z); o.w = f2bf(v.w);
    reinterpret_cast<ushort4*>(xb)[i] = o;
  }
}

// ---------- kernel 2: W_eff = (W_q - zero)*scale + 2*(A@B)^T, bf16 ----------
__global__ __launch_bounds__(256) void build_weff_kernel(
    const int* __restrict__ Wq, const float* __restrict__ scale,
    const float* __restrict__ zero, const float* __restrict__ A,
    const float* __restrict__ Bm, unsigned short* __restrict__ Weff) {
  __shared__ float sA[64 * 17];
  __shared__ float sB[16 * 64];
  int bo = blockIdx.x >> 6;
  int bi = blockIdx.x & 63;
  int o0 = bo * 64, i0 = bi * 64;
  int t = threadIdx.x;
  for (int j = t; j < 1024; j += 256) sA[(j >> 4) * 17 + (j & 15)] = A[i0 * 16 + j];
  for (int j = t; j < 1024; j += 256) sB[j] = Bm[(j >> 6) * N_DIM + o0 + (j & 63)];
  __syncthreads();
  for (int e = 0; e < 16; ++e) {
    int idx = e * 256 + t;
    int oo = idx >> 6, ii = idx & 63;
    int o = o0 + oo;
    float sc = scale[o * 64 + bi];
    float zp = zero[o * 64 + bi];
    float w = ((float)Wq[(size_t)o * K_DIM + i0 + ii] - zp) * sc;
    float acc = 0.f;
#pragma unroll
    for (int r = 0; r < 16; ++r) acc += sA[ii * 17 + r] * sB[r * 64 + oo];
    w += 2.0f * acc;
    Weff[(size_t)o * K_DIM + i0 + ii] = f2bf(w);
  }
}

// ---------- kernel 3: 256x256 8-phase bf16 GEMM (T1+T2+T3+T4+T5) ----------
#define BAR() __builtin_amdgcn_s_barrier()
#define SB()  __builtin_amdgcn_sched_barrier(0)
#define WAIT_LGKM() do { asm volatile("s_waitcnt lgkmcnt(0)" ::: "memory"); SB(); } while (0)
#define WAIT_VM4()  do { asm volatile("s_waitcnt vmcnt(4)" ::: "memory"); } while (0)

// swizzled LDS fragment read: region is a [128][64] bf16 half-tile; chunk c (16B)
// lives at column (c ^ (row&7)) -- matches the pre-swizzled global staging below.
__device__ __forceinline__ bf16x8 lds_frag(const unsigned short* region, int row, int c) {
  return *reinterpret_cast<const bf16x8*>(region + row * 64 + ((c ^ (row & 7)) << 3));
}

__device__ __forceinline__ void readA(const unsigned short* reg, int mh, int lc, int lr,
                                      bf16x8 a[4][2]) {
#pragma unroll
  for (int m = 0; m < 4; ++m) {
    int row = mh * 64 + m * 16 + lc;
#pragma unroll
    for (int kk = 0; kk < 2; ++kk) a[m][kk] = lds_frag(reg, row, kk * 4 + lr);
  }
}

__device__ __forceinline__ void readB(const unsigned short* reg, int nh, int rB, int lc, int lr,
                                      bf16x8 b[2][2]) {
#pragma unroll
  for (int n = 0; n < 2; ++n) {
    int row = rB + (nh * 2 + n) * 16 + lc;
#pragma unroll
    for (int kk = 0; kk < 2; ++kk) b[n][kk] = lds_frag(reg, row, kk * 4 + lr);
  }
}

__device__ __forceinline__ void mfma_quad(const bf16x8 a[4][2], const bf16x8 b[2][2],
                                          f32x4 acc[8][4], int mh, int nh) {
  __builtin_amdgcn_s_setprio(1);
#pragma unroll
  for (int m = 0; m < 4; ++m)
#pragma unroll
    for (int n = 0; n < 2; ++n)
#pragma unroll
      for (int kk = 0; kk < 2; ++kk)
        acc[mh * 4 + m][nh * 2 + n] = __builtin_amdgcn_mfma_f32_16x16x32_bf16(
            a[m][kk], b[n][kk], acc[mh * 4 + m][nh * 2 + n], 0, 0, 0);
  __builtin_amdgcn_s_setprio(0);
}

__global__ __launch_bounds__(512, 2) void gemm_kernel(
    const unsigned short* __restrict__ xb, const unsigned short* __restrict__ wb,
    const float* __restrict__ bias, float* __restrict__ out) {
  // LDS: 2 buffers x [A: 2x(128x64) | B: 2x(128x64)] bf16 = 128 KiB
  __shared__ unsigned short lds[65536];

  int bid = blockIdx.x;
  int swz = (bid & 7) * 64 + (bid >> 3);   // bijective: 512 % 8 == 0
  int mt = swz >> 4, nt = swz & 15;
  int m0 = mt * 256, n0 = nt * 256;

  int tid = threadIdx.x;
  int w = tid >> 6, lane = tid & 63;
  int wr = w >> 2, wc = w & 3;             // 2 x 4 waves; per-wave out = 128x64
  int lr = lane >> 4, lc = lane & 15;

  // staging geometry: chunk = l*512 + tid (16B chunks), row = chunk>>3,
  // physical col = chunk&7, logical (global) col = (chunk&7) ^ (row&7)
  int r0 = tid >> 3, c0g = (tid & 7) ^ (r0 & 7);
  int ch1 = 512 + tid;
  int r1 = ch1 >> 3, c1g = (ch1 & 7) ^ (r1 & 7);
  int co0 = tid * 8, co1 = ch1 * 8;        // linear LDS dst offsets (ushort)

  const unsigned short* sA[2][2];
  const unsigned short* sB[2][2];
  sA[0][0] = xb + (size_t)(m0 + r0) * K_DIM + c0g * 8;
  sA[0][1] = xb + (size_t)(m0 + r1) * K_DIM + c1g * 8;
  sA[1][0] = xb + (size_t)(m0 + 128 + r0) * K_DIM + c0g * 8;
  sA[1][1] = xb + (size_t)(m0 + 128 + r1) * K_DIM + c1g * 8;
  sB[0][0] = wb + (size_t)(n0 + r0) * K_DIM + c0g * 8;
  sB[0][1] = wb + (size_t)(n0 + r1) * K_DIM + c1g * 8;
  sB[1][0] = wb + (size_t)(n0 + 128 + r0) * K_DIM + c0g * 8;
  sB[1][1] = wb + (size_t)(n0 + 128 + r1) * K_DIM + c1g * 8;

#define STAGE_A(h, buf, kt) do { \
    async_copy16(sA[h][0] + (kt), &lds[(buf) * 32768 + (h) * 8192 + co0]); \
    async_copy16(sA[h][1] + (kt), &lds[(buf) * 32768 + (h) * 8192 + co1]); } while (0)
#define STAGE_B(h, buf, kt) do { \
    async_copy16(sB[h][0] + (kt), &lds[(buf) * 32768 + 16384 + (h) * 8192 + co0]); \
    async_copy16(sB[h][1] + (kt), &lds[(buf) * 32768 + 16384 + (h) * 8192 + co1]); } while (0)

  const unsigned short* aR[2] = { &lds[wr * 8192], &lds[32768 + wr * 8192] };
  const unsigned short* bR[2] = { &lds[16384 + (wc >> 1) * 8192],
                                  &lds[32768 + 16384 + (wc >> 1) * 8192] };
  int rB = (wc & 1) * 64;

  f32x4 acc[8][4];
#pragma unroll
  for (int i = 0; i < 8; ++i)
#pragma unroll
    for (int j = 0; j < 4; ++j) acc[i][j] = f32x4{0.f, 0.f, 0.f, 0.f};

  // prologue: tile0 fully into buf0, then Bh0/Ah0 of tile1 into buf1
  STAGE_A(0, 0, 0); STAGE_A(1, 0, 0); STAGE_B(0, 0, 0); STAGE_B(1, 0, 0);
  STAGE_B(0, 1, 64); STAGE_A(0, 1, 64);
  WAIT_VM4(); BAR(); SB();

  bf16x8 a[4][2], b0[2][2], b1[2][2];

#pragma unroll 1
  for (int i = 0; i < 32; ++i) {
    int k1 = (2 * i + 1) * 64;             // tile t+1 (never wraps)
    int k2 = ((2 * i + 2) & 63) * 64;      // tile t+2 (wraps harmlessly at end)
    int k3 = ((2 * i + 3) & 63) * 64;      // tile t+3

    // P1: tile t Q(0,0)          stage Ah1(t+1)->buf1
    readA(aR[0], 0, lc, lr, a); readB(bR[0], 0, rB, lc, lr, b0);
    STAGE_A(1, 1, k1);
    SB(); BAR(); WAIT_LGKM();
    mfma_quad(a, b0, acc, 0, 0);
    SB(); BAR(); SB();
    // P2: Q(0,1)                 stage Bh1(t+1)->buf1
    readB(bR[0], 1, rB, lc, lr, b1);
    STAGE_B(1, 1, k1);
    SB(); BAR(); WAIT_LGKM();
    mfma_quad(a, b1, acc, 0, 1);
    SB(); BAR(); SB();
    // P3: Q(1,1)                 stage Bh0(t+2)->buf0 (B(t) last read P2)
    readA(aR[0], 1, lc, lr, a);
    STAGE_B(0, 0, k2);
    SB(); BAR(); WAIT_LGKM();
    mfma_quad(a, b1, acc, 1, 1);
    SB(); BAR(); SB();
    // P4: Q(1,0)                 stage Ah0(t+2)->buf0 (A(t) last read P3); seam wait
    STAGE_A(0, 0, k2);
    SB(); BAR();
    mfma_quad(a, b0, acc, 1, 0);
    SB(); WAIT_VM4(); BAR(); SB();       // tile t+1 fully landed (2 half-tiles in flight)
    // P5: tile t+1 Q(0,0)        stage Ah1(t+2)->buf0
    readA(aR[1], 0, lc, lr, a); readB(bR[1], 0, rB, lc, lr, b0);
    STAGE_A(1, 0, k2);
    SB(); BAR(); WAIT_LGKM();
    mfma_quad(a, b0, acc, 0, 0);
    SB(); BAR(); SB();
    // P6: Q(0,1)                 stage Bh1(t+2)->buf0
    readB(bR[1], 1, rB, lc, lr, b1);
    STAGE_B(1, 0, k2);
    SB(); BAR(); WAIT_LGKM();
    mfma_quad(a, b1, acc, 0, 1);
    SB(); BAR(); SB();
    // P7: Q(1,1)                 stage Bh0(t+3)->buf1 (B(t+1) last read P6)
    readA(aR[1], 1, lc, lr, a);
    STAGE_B(0, 1, k3);
    SB(); BAR(); WAIT_LGKM();
    mfma_quad(a, b1, acc, 1, 1);
    SB(); BAR(); SB();
    // P8: Q(1,0)                 stage Ah0(t+3)->buf1 (A(t+1) last read P7); seam wait
    STAGE_A(0, 1, k3);
    SB(); BAR();
    mfma_quad(a, b0, acc, 1, 0);
    SB(); WAIT_VM4(); BAR(); SB();       // tile t+2 fully landed
  }

  // epilogue: C/D layout col=lane&15, row=(lane>>4)*4+j
#pragma unroll
  for (int ni = 0; ni < 4; ++ni) {
    int n = n0 + wc * 64 + ni * 16 + lc;
    float bv = bias[n];
#pragma unroll
    for (int mi = 0; mi < 8; ++mi) {
      int mb = m0 + wr * 128 + mi * 16 + lr * 4;
#pragma unroll
      for (int j = 0; j < 4; ++j)
        out[(size_t)(mb + j) * N_DIM + n] = acc[mi][ni][j] + bv;
    }
  }
#undef STAGE_A
#undef STAGE_B
}

extern "C" void kernel_launch(void* const* d_in, const int* in_sizes, int n_in,
                              void* d_out, int out_size, void* d_ws, size_t ws_size,
                              hipStream_t stream) {
  const float* x     = (const float*)d_in[0];
  const int*   Wq    = (const int*)d_in[1];
  const float* scale = (const float*)d_in[2];
  const float* zero  = (const float*)d_in[3];
  const float* lA    = (const float*)d_in[4];
  const float* lB    = (const float*)d_in[5];
  const float* bias  = (const float*)d_in[6];
  float* out = (float*)d_out;

  unsigned short* xb = (unsigned short*)d_ws;                                      // 64 MB
  unsigned short* wb = (unsigned short*)((char*)d_ws + (size_t)M_DIM * K_DIM * 2); // +32 MB

  cvt_x_kernel<<<2048, 256, 0, stream>>>(x, xb, (M_DIM * K_DIM) / 4);
  build_weff_kernel<<<4096, 256, 0, stream>>>(Wq, scale, zero, lA, lB, wb);
  gemm_kernel<<<512, 512, 0, stream>>>(xb, wb, bias, out);
}